// Round 16
// baseline (114.064 us; speedup 1.0000x reference)
//
#include <hip/hip_runtime.h>
#include <hip/hip_fp16.h>
#include <math.h>

// Problem constants
#define T_LEN 131072
#define NCH   32
#define NBAT  4
#define WIN   512
#define HOP   256
#define NFR   512            // frames per (b,c) = T/HOP
#define NBIN  257            // rfft bins
#define NBC   (NBAT*NCH)     // 128
#define FPB   4              // frames per chunk (one wave per chunk)
#define NBLK  (NFR/FPB)      // 128 chunks per bc
#define TWOPI 6.28318530717958647692f

// XOR swizzle for FFT LDS complex arrays (hits the b64 4-lane/bank floor)
#define SWZ(m) ((m) ^ ((((m) >> 4) & 15)))

// Packed complex type: clang emits v_pk_{add,mul,fma}_f32 for ext_vector
// float2 arithmetic on CDNA — halves VALU instruction count vs scalar pairs.
typedef float v2f __attribute__((ext_vector_type(2)));

__device__ __forceinline__ v2f cmulv(v2f u, v2f v) {
  // (ux vx - uy vy, ux vy + uy vx) = u.xx*v + (-uy, uy)*v.yx  -> 2 pk_fma
  v2f r = u.xx * v;
  return __builtin_elementwise_fma((v2f){-u.y, u.y}, v.yx, r);
}

__device__ __forceinline__ float fast_tanh(float x) {
  float e = __expf(2.0f * x);                    // inf-safe
  return 1.0f - 2.0f * __builtin_amdgcn_rcpf(e + 1.0f);
}

__device__ __forceinline__ v2f h2v(__half2 h) {
  float2 f = __half22float2(h);
  return (v2f){f.x, f.y};
}
__device__ __forceinline__ __half2 v2h(v2f v) {
  return __float22half2_rn(make_float2(v.x, v.y));
}

// Cross-lane pull via the LDS crossbar (no LDS storage, no fences, no
// bank conflicts). R10-proven form: extract scalars, __float_as_int.
__device__ __forceinline__ v2f bperm2(int addr, v2f v) {
  float fx = v.x, fy = v.y;
  int vx = __builtin_amdgcn_ds_bpermute(addr, __float_as_int(fx));
  int vy = __builtin_amdgcn_ds_bpermute(addr, __float_as_int(fy));
  return (v2f){__int_as_float(vx), __int_as_float(vy)};
}

// Wave-level ordering fence: LDS ops of a wave execute in order on the DS
// pipe; this only stops compiler reordering (no s_barrier, no cnt drain).
__device__ __forceinline__ void wave_sync() {
  asm volatile("" ::: "memory");
  __builtin_amdgcn_wave_barrier();
  asm volatile("" ::: "memory");
}

// radix-4 DIF butterfly (packed): t1 = amc - i*bmd, t3 = amc + i*bmd
__device__ __forceinline__ void r4bf(v2f a, v2f b, v2f c, v2f d,
                                     v2f& y0, v2f& t1, v2f& t2, v2f& t3) {
  const v2f PM = {1.f, -1.f};
  const v2f MP = {-1.f, 1.f};
  v2f apc = a + c, amc = a - c;
  v2f bpd = b + d, bmd = b - d;
  y0 = apc + bpd;
  t2 = apc - bpd;
  v2f bs = bmd.yx;
  t1 = __builtin_elementwise_fma(bs, PM, amc);   // (amc.x+bmd.y, amc.y-bmd.x)
  t3 = __builtin_elementwise_fma(bs, MP, amc);   // (amc.x-bmd.y, amc.y+bmd.x)
}

// Per-stage base twiddles only (6 VGPRs); w2, w3 recomputed inline (R11).
struct TW {
  v2f a1, b1, c1;
};

__device__ __forceinline__ void load_tw(const v2f* __restrict__ W256f, int lane, TW& t) {
  t.a1 = W256f[lane];
  t.b1 = W256f[4 * (lane >> 2)];
  t.c1 = W256f[16 * (lane >> 4)];
}

// 256-pt forward complex FFT. Input regs z0..z3 = z[lane+64m]; output regs
// z0..z3 = Z[lane+64m]. Stages 0 & 3 in registers; 1 & 2 via wave-private LDS.
__device__ __forceinline__ void fft256_reg(v2f& z0, v2f& z1, v2f& z2, v2f& z3,
                                           v2f* __restrict__ buf, int lane, const TW& tw) {
  v2f y0, t1, t2, t3;
  // stage 0 (s=1, p=lane): pure register butterfly, scatter 4l..4l+3
  r4bf(z0, z1, z2, z3, y0, t1, t2, t3);
  {
    v2f w1 = tw.a1, w2 = cmulv(w1, w1), w3 = cmulv(w1, w2);
    int o0 = 4 * lane;
    buf[SWZ(o0)]     = y0;
    buf[SWZ(o0 + 1)] = cmulv(w1, t1);
    buf[SWZ(o0 + 2)] = cmulv(w2, t2);
    buf[SWZ(o0 + 3)] = cmulv(w3, t3);
  }
  wave_sync();
  // stage 1 (s=4)
  {
    v2f a = buf[SWZ(lane)], b = buf[SWZ(lane + 64)],
        c = buf[SWZ(lane + 128)], d = buf[SWZ(lane + 192)];
    wave_sync();
    r4bf(a, b, c, d, y0, t1, t2, t3);
    v2f w1 = tw.b1, w2 = cmulv(w1, w1), w3 = cmulv(w1, w2);
    int o = lane + 12 * (lane >> 2);
    buf[SWZ(o)]      = y0;
    buf[SWZ(o + 4)]  = cmulv(w1, t1);
    buf[SWZ(o + 8)]  = cmulv(w2, t2);
    buf[SWZ(o + 12)] = cmulv(w3, t3);
  }
  wave_sync();
  // stage 2 (s=16)
  {
    v2f a = buf[SWZ(lane)], b = buf[SWZ(lane + 64)],
        c = buf[SWZ(lane + 128)], d = buf[SWZ(lane + 192)];
    wave_sync();
    r4bf(a, b, c, d, y0, t1, t2, t3);
    v2f w1 = tw.c1, w2 = cmulv(w1, w1), w3 = cmulv(w1, w2);
    int o = lane + 48 * (lane >> 4);
    buf[SWZ(o)]      = y0;
    buf[SWZ(o + 16)] = cmulv(w1, t1);
    buf[SWZ(o + 32)] = cmulv(w2, t2);
    buf[SWZ(o + 48)] = cmulv(w3, t3);
  }
  wave_sync();
  // stage 3 (s=64, p=0, twiddle-free): outputs land in register layout
  {
    v2f a = buf[SWZ(lane)], b = buf[SWZ(lane + 64)],
        c = buf[SWZ(lane + 128)], d = buf[SWZ(lane + 192)];
    wave_sync();
    r4bf(a, b, c, d, z0, z1, z2, z3);
  }
}

// W256f[m] = exp(-2pi i m/256), m<256 ; W512s[k] = exp(-2pi i k/512), k<=256
__device__ __forceinline__ void build_tables(v2f* W256f, v2f* W512s) {
  int tid = threadIdx.x;
  float sv, cv;
  __sincosf(-(TWOPI / 256.0f) * (float)tid, &sv, &cv);
  W256f[tid] = (v2f){cv, sv};
  __sincosf(-(TWOPI / 512.0f) * (float)tid, &sv, &cv);
  W512s[tid] = (v2f){cv, sv};
  if (tid == 0) W512s[256] = (v2f){-1.f, 0.f};
}

// ---------------------------------------------------------------------------
// 1) channel mix: y[b,d,t] = sum_c x[b,c,t] * mixer[c,d]   (fp16 output)
//    mixer read directly (wave-uniform -> scalar loads via K$).
// ---------------------------------------------------------------------------
__global__ __launch_bounds__(256) void mix_kernel(const float* __restrict__ x,
                                                  const float* __restrict__ mixer,
                                                  __half2* __restrict__ y) {
  int b = blockIdx.y;
  int t2 = blockIdx.x * 256 + threadIdx.x;     // float2-pair index
  const float2* xv = (const float2*)x;
  float2 xr[NCH];
#pragma unroll
  for (int c = 0; c < NCH; c++)
    xr[c] = xv[(((size_t)(b * NCH + c)) * T_LEN >> 1) + t2];
#pragma unroll 4
  for (int d = 0; d < NCH; d++) {
    float ax = 0.f, ay = 0.f;
#pragma unroll
    for (int c = 0; c < NCH; c++) {
      float m = mixer[c * NCH + d];            // uniform -> s_load
      ax = fmaf(xr[c].x, m, ax);
      ay = fmaf(xr[c].y, m, ay);
    }
    y[(((size_t)(b * NCH + d)) * T_LEN >> 1) + t2] = __float22half2_rn(make_float2(ax, ay));
  }
}

// ---------------------------------------------------------------------------
// 2) forward rfft(512) + register-local scan. Wave = one 4-frame chunk.
//    (R13-exact: LDS mirror staging)
// ---------------------------------------------------------------------------
__global__ __launch_bounds__(256, 3) void fft_fwd_kernel(const __half2* __restrict__ y,
                                                         const float* __restrict__ transfer,
                                                         __half2* __restrict__ spec) {
  __shared__ v2f fbuf[4][NBIN];          // wave-private FFT/mirror buffer
  __shared__ v2f W256f[256];
  __shared__ v2f W512s[NBIN];
  build_tables(W256f, W512s);
  __syncthreads();
  const v2f PM = {1.f, -1.f};
  int wave = threadIdx.x >> 6, lane = threadIdx.x & 63;
  int cid = blockIdx.x * 4 + wave;       // chunk id 0..16383
  int bc = cid >> 7, blk = cid & (NBLK - 1);
  int ch = bc & (NCH - 1);
  v2f* buf = fbuf[wave];
  TW tw; load_tw(W256f, lane, tw);
  v2f Wf[4];
  float trq[4];
#pragma unroll
  for (int q = 0; q < 4; q++) {
    int k = lane + 64 * q;
    Wf[q] = W512s[k];                    // (cw, sw)
    trq[q] = transfer[ch * NBIN + k];
  }
  float tr256 = transfer[ch * NBIN + 256];
  v2f s[4] = {(v2f){0,0}, (v2f){0,0}, (v2f){0,0}, (v2f){0,0}};
  float s256x = 0.f;
  size_t base2 = ((size_t)bc * T_LEN + (size_t)blk * (FPB * HOP)) >> 1;  // half2 idx
  size_t fb = ((size_t)bc * NFR + (size_t)blk * FPB) * NBIN;
  bool lastchunk = (blk == NBLK - 1);
#pragma unroll
  for (int j = 0; j < FPB; ++j) {
    const __half2* src = y + base2 + (size_t)j * (HOP / 2);
    // pack: z[n] = (y[2n], y[2n+1]) for n = lane+64q — one half2 load each
    v2f z0 = h2v(src[lane]);
    v2f z1 = h2v(src[lane + 64]);
    v2f z2, z3;
    if (lastchunk && j == FPB - 1) {     // zero-padded final half-window
      z2 = (v2f){0, 0}; z3 = (v2f){0, 0};
    } else {
      z2 = h2v(src[lane + 128]);
      z3 = h2v(src[lane + 192]);
    }
    fft256_reg(z0, z1, z2, z3, buf, lane, tw);
    // stage Z (regs) for mirror access
    buf[lane] = z0; buf[lane + 64] = z1; buf[lane + 128] = z2; buf[lane + 192] = z3;
    wave_sync();
    v2f zm0 = buf[(256 - lane) & 255];
    v2f zm1 = buf[192 - lane];
    v2f zm2 = buf[128 - lane];
    v2f zm3 = buf[64 - lane];
    v2f z0b = buf[0];
    wave_sync();
    // untangle + scan + store, k = lane + 64q   (all packed)
#pragma unroll
    for (int q = 0; q < 4; q++) {
      v2f zk  = (q == 0) ? z0 : (q == 1) ? z1 : (q == 2) ? z2 : z3;
      v2f zmk = (q == 0) ? zm0 : (q == 1) ? zm1 : (q == 2) ? zm2 : zm3;
      v2f E = __builtin_elementwise_fma(zmk, PM, zk) * 0.5f;    // (zx+zmx, zy-zmy)/2
      v2f D = __builtin_elementwise_fma(zmk, -PM, zk) * 0.5f;   // (zx-zmx, zy+zmy)/2
      v2f O = D.yx * PM;                                        // (dy, -dx)
      v2f Y = E + cmulv(Wf[q], O);
      s[q] = (Y + s[q]) * trq[q];
      spec[fb + (size_t)j * NBIN + lane + 64 * q] = v2h(s[q]);
    }
    // bin 256: zk = zmk = Z[0], cw=-1, sw=0 -> Y = (Z0.x - Z0.y, 0)
    s256x = tr256 * ((z0b.x - z0b.y) + s256x);
    if (lane == 0) spec[fb + (size_t)j * NBIN + 256] = v2h((v2f){s256x, 0.f});
    wave_sync();
  }
}

// ---------------------------------------------------------------------------
// 3) carry scan across chunks: C[0]=0; C[i] = final[i-1] + tr^FPB * C[i-1]
// ---------------------------------------------------------------------------
__global__ __launch_bounds__(256) void carry_kernel(const __half2* __restrict__ spec,
                                                    const float* __restrict__ transfer,
                                                    __half2* __restrict__ carries) {
  int tid = blockIdx.x * 256 + threadIdx.x;
  if (tid >= NBC * NBIN) return;
  int bc = tid / NBIN, k = tid - bc * NBIN;
  int ch = bc & (NCH - 1);
  float tr = transfer[ch * NBIN + k];
  float tr2 = tr * tr;
  float tr4 = tr2 * tr2;          // tr^FPB
  const __half2* fin = spec + (size_t)bc * NFR * NBIN + (size_t)(FPB - 1) * NBIN + k;
  __half2* cp = carries + (size_t)bc * NBLK * NBIN + k;
  v2f c = {0.f, 0.f};
  for (int i = 0; i < NBLK; i += 16) {
    v2f v[16];
#pragma unroll
    for (int u = 0; u < 16; u++) v[u] = h2v(fin[(size_t)(i + u) * FPB * NBIN]);
#pragma unroll
    for (int u = 0; u < 16; u++) {
      cp[(size_t)(i + u) * NBIN] = v2h(c);
      c = __builtin_elementwise_fma((v2f){tr4, tr4}, c, v[u]);
    }
  }
}

// ---------------------------------------------------------------------------
// 4) inverse rfft + hann + register OLA. Wave = one 4-frame chunk.
//    Mirror via ds_bpermute (registers only) — isolated change vs R13.
// ---------------------------------------------------------------------------
__global__ __launch_bounds__(256, 3) void fft_inv_kernel(const __half2* __restrict__ spec,
                                                         const __half2* __restrict__ carries,
                                                         const float* __restrict__ transfer,
                                                         const float* __restrict__ gain,
                                                         float* __restrict__ out,
                                                         __half2* __restrict__ bnd) {
  __shared__ v2f fbuf[4][NBIN];
  __shared__ v2f W256f[256];
  __shared__ v2f W512s[NBIN];
  build_tables(W256f, W512s);
  __syncthreads();
  const v2f PM = {1.f, -1.f};
  int wave = threadIdx.x >> 6, lane = threadIdx.x & 63;
  int cid = blockIdx.x * 4 + wave;
  int bc = cid >> 7, blk = cid & (NBLK - 1);
  int ch = bc & (NCH - 1);
  v2f* buf = fbuf[wave];
  TW tw; load_tw(W256f, lane, tw);
  const __half2* crp = carries + ((size_t)bc * NBLK + blk) * NBIN;
  v2f Wi[4], cv[4], hv[4];
  float trq[4], trp[4];
#pragma unroll
  for (int q = 0; q < 4; q++) {
    int k = lane + 64 * q;
    Wi[q] = W512s[k] * PM;               // (cw, -sw) = exp(+2pi i k/512)
    trq[q] = transfer[ch * NBIN + k];
    trp[q] = trq[q];
    cv[q] = h2v(crp[k]);
    int t0 = 2 * k, t1 = 2 * k + 1;
    int i0 = (t0 <= 256) ? t0 : 512 - t0;
    int i1 = (t1 <= 256) ? t1 : 512 - t1;
    float h0 = (0.5f - 0.5f * W512s[i0].x) * (1.0f / 256.0f);
    float h1 = (0.5f - 0.5f * W512s[i1].x) * (1.0f / 256.0f);
    hv[q] = (v2f){h0, -h1};              // window + conj fold: w = z * (h0, -h1)
  }
  float tr256 = transfer[ch * NBIN + 256], trp256 = tr256;
  v2f cv256 = h2v(crp[256]);
  float g = gain[ch];
  const __half2* sp0 = spec + ((size_t)bc * NFR + (size_t)blk * FPB) * NBIN;
  float2* outv = (float2*)out;
  size_t obase2 = ((size_t)bc * T_LEN + (size_t)blk * (FPB * HOP)) >> 1;
  __half2* bp = bnd + (((size_t)bc * NBLK + blk) * 2) * (HOP / 2);
  int maddr = ((64 - lane) & 63) << 2;   // bpermute byte addr: src lane 64-l
  v2f pt0, pt1;                          // previous frame's windowed tail
#pragma unroll
  for (int j = 0; j < FPB; ++j) {
    const __half2* sp = sp0 + (size_t)j * NBIN;
    // load + carry fix-up: O = local + tr^(j+1) * carry   (packed fma)
    v2f Y0 = __builtin_elementwise_fma((v2f){trp[0], trp[0]}, cv[0], h2v(sp[lane]));
    v2f Y1 = __builtin_elementwise_fma((v2f){trp[1], trp[1]}, cv[1], h2v(sp[lane + 64]));
    v2f Y2 = __builtin_elementwise_fma((v2f){trp[2], trp[2]}, cv[2], h2v(sp[lane + 128]));
    v2f Y3 = __builtin_elementwise_fma((v2f){trp[3], trp[3]}, cv[3], h2v(sp[lane + 192]));
    v2f y256 = __builtin_elementwise_fma((v2f){trp256, trp256}, cv256, h2v(sp[256]));
#pragma unroll
    for (int q = 0; q < 4; q++) trp[q] *= trq[q];
    trp256 *= tr256;
    // mirror via crossbar: ym[q] = Y[256-k], k = lane+64q
    //   lane>=1: 256-(lane+64q) = 64(3-q) + (64-lane) -> reg (3-q) @ lane 64-lane
    //   lane==0: Y[256-64q] -> fixups from own regs / y256
    v2f ym0 = bperm2(maddr, Y3);
    v2f ym1 = bperm2(maddr, Y2);
    v2f ym2 = bperm2(maddr, Y1);
    v2f ym3 = bperm2(maddr, Y0);
    if (lane == 0) { ym0 = y256; ym1 = Y3; ym2 = Y2; ym3 = Y1; }
    // inverse untangle -> conj'd FFT input:  z = E*PM - O.yx   (packed)
    v2f z0, z1, z2, z3;
#pragma unroll
    for (int q = 0; q < 4; q++) {
      v2f yk  = (q == 0) ? Y0 : (q == 1) ? Y1 : (q == 2) ? Y2 : Y3;
      v2f ymk = (q == 0) ? ym0 : (q == 1) ? ym1 : (q == 2) ? ym2 : ym3;
      v2f E = __builtin_elementwise_fma(ymk, PM, yk) * 0.5f;
      v2f D = __builtin_elementwise_fma(ymk, -PM, yk) * 0.5f;
      v2f O = cmulv(Wi[q], D);           // (dx cw - dy sw, dx sw + dy cw)
      v2f zq = E * PM - O.yx;            // (Ex - Oy, -(Ey + Ox))
      if (q == 0) z0 = zq; else if (q == 1) z1 = zq; else if (q == 2) z2 = zq; else z3 = zq;
    }
    fft256_reg(z0, z1, z2, z3, buf, lane, tw);
    // windowed time samples: w = z * (h0, -h1)   (conj + /256 folded in)
    v2f w0 = z0 * hv[0];
    v2f w1 = z1 * hv[1];
    v2f w2 = z2 * hv[2];
    v2f w3 = z3 * hv[3];
    if (j == 0) {
      bp[lane]      = v2h(w0);           // chunk-leading head -> bnd
      bp[lane + 64] = v2h(w1);
    } else {
      v2f v0 = pt0 + w0;
      v2f v1 = pt1 + w1;
      outv[obase2 + (size_t)j * 128 + lane] =
          make_float2(fast_tanh(g * v0.x), fast_tanh(g * v0.y));
      outv[obase2 + (size_t)j * 128 + lane + 64] =
          make_float2(fast_tanh(g * v1.x), fast_tanh(g * v1.y));
    }
    pt0 = w2; pt1 = w3;
    wave_sync();                         // next frame's stage-0 writes wait
  }
  bp[128 + lane] = v2h(pt0);             // chunk-trailing tail -> bnd
  bp[192 + lane] = v2h(pt1);
}

// ---------------------------------------------------------------------------
// 5) combine boundary chunks: chunk FPB*b <- bnd[b-1].tail + bnd[b].head
// ---------------------------------------------------------------------------
__global__ __launch_bounds__(256) void final_kernel(const __half* __restrict__ bnd,
                                                    const float* __restrict__ gain,
                                                    float* __restrict__ out) {
  int bc = blockIdx.y, b = blockIdx.x;
  int s = threadIdx.x;
  const __half* base = bnd + ((size_t)bc * NBLK) * 2 * HOP;
  float v = __half2float(base[((size_t)b * 2) * HOP + s]);
  if (b > 0) v += __half2float(base[((size_t)(b - 1) * 2 + 1) * HOP + s]);
  float g = gain[bc & (NCH - 1)];
  out[(size_t)bc * T_LEN + (size_t)b * (FPB * HOP) + s] = fast_tanh(g * v);
}

// ---------------------------------------------------------------------------
extern "C" void kernel_launch(void* const* d_in, const int* in_sizes, int n_in,
                              void* d_out, int out_size, void* d_ws, size_t ws_size,
                              hipStream_t stream) {
  (void)in_sizes; (void)n_in; (void)out_size; (void)ws_size;
  const float* x        = (const float*)d_in[0];
  const float* transfer = (const float*)d_in[1];
  const float* mixer    = (const float*)d_in[2];
  const float* gain     = (const float*)d_in[3];
  float* out = (float*)d_out;

  // ws layout (all fp16):
  //  [spec 67,371,008 B][bnd 16,777,216 B][carries 16,842,752 B][y 33,554,432 B]
  char* p = (char*)d_ws;
  __half2* spec    = (__half2*)p;                       p += (size_t)NBC * NFR * NBIN * 4;
  __half2* bnd     = (__half2*)p;                       p += (size_t)NBC * NBLK * 2 * HOP * 2;
  __half2* carries = (__half2*)p;                       p += (size_t)NBC * NBLK * NBIN * 4;
  __half2* y       = (__half2*)p;

  mix_kernel<<<dim3(T_LEN / 512, NBAT), 256, 0, stream>>>(x, mixer, y);
  fft_fwd_kernel<<<dim3(NBC * NBLK / 4), 256, 0, stream>>>(y, transfer, spec);
  carry_kernel<<<dim3((NBC * NBIN + 255) / 256), 256, 0, stream>>>(spec, transfer, carries);
  fft_inv_kernel<<<dim3(NBC * NBLK / 4), 256, 0, stream>>>(spec, carries, transfer, gain, out, (__half2*)bnd);
  final_kernel<<<dim3(NBLK, NBC), 256, 0, stream>>>((const __half*)bnd, gain, out);
}

// Round 17
// 109.214 us; speedup vs baseline: 1.0444x; 1.0444x over previous
//
#include <hip/hip_runtime.h>
#include <hip/hip_fp16.h>
#include <math.h>

// Problem constants
#define T_LEN 131072
#define NCH   32
#define NBAT  4
#define WIN   512
#define HOP   256
#define NFR   512            // frames per (b,c) = T/HOP
#define NBIN  257            // rfft bins
#define NBC   (NBAT*NCH)     // 128
#define FPB   4              // frames per chunk (one wave per chunk)
#define NBLK  (NFR/FPB)      // 128 chunks per bc
#define TWOPI 6.28318530717958647692f

// XOR swizzle for FFT LDS complex arrays (hits the b64 4-lane/bank floor)
#define SWZ(m) ((m) ^ ((((m) >> 4) & 15)))

// Packed complex type: clang emits v_pk_{add,mul,fma}_f32 for ext_vector
// float2 arithmetic on CDNA — halves VALU instruction count vs scalar pairs.
typedef float v2f __attribute__((ext_vector_type(2)));

__device__ __forceinline__ v2f cmulv(v2f u, v2f v) {
  // (ux vx - uy vy, ux vy + uy vx) = u.xx*v + (-uy, uy)*v.yx  -> 2 pk_fma
  v2f r = u.xx * v;
  return __builtin_elementwise_fma((v2f){-u.y, u.y}, v.yx, r);
}

__device__ __forceinline__ float fast_tanh(float x) {
  float e = __expf(2.0f * x);                    // inf-safe
  return 1.0f - 2.0f * __builtin_amdgcn_rcpf(e + 1.0f);
}

__device__ __forceinline__ v2f h2v(__half2 h) {
  float2 f = __half22float2(h);
  return (v2f){f.x, f.y};
}
__device__ __forceinline__ __half2 v2h(v2f v) {
  return __float22half2_rn(make_float2(v.x, v.y));
}

// Cross-lane pull via the LDS crossbar (no LDS storage, no fences, no
// bank conflicts). R10/R15-proven form: extract scalars, __float_as_int.
__device__ __forceinline__ v2f bperm2(int addr, v2f v) {
  float fx = v.x, fy = v.y;
  int vx = __builtin_amdgcn_ds_bpermute(addr, __float_as_int(fx));
  int vy = __builtin_amdgcn_ds_bpermute(addr, __float_as_int(fy));
  return (v2f){__int_as_float(vx), __int_as_float(vy)};
}

// Wave-level ordering fence: LDS ops of a wave execute in order on the DS
// pipe; this only stops compiler reordering (no s_barrier, no cnt drain).
// Burst global loads are issued BEFORE the loop so they stay in flight.
__device__ __forceinline__ void wave_sync() {
  asm volatile("" ::: "memory");
  __builtin_amdgcn_wave_barrier();
  asm volatile("" ::: "memory");
}

// radix-4 DIF butterfly (packed): t1 = amc - i*bmd, t3 = amc + i*bmd
__device__ __forceinline__ void r4bf(v2f a, v2f b, v2f c, v2f d,
                                     v2f& y0, v2f& t1, v2f& t2, v2f& t3) {
  const v2f PM = {1.f, -1.f};
  const v2f MP = {-1.f, 1.f};
  v2f apc = a + c, amc = a - c;
  v2f bpd = b + d, bmd = b - d;
  y0 = apc + bpd;
  t2 = apc - bpd;
  v2f bs = bmd.yx;
  t1 = __builtin_elementwise_fma(bs, PM, amc);   // (amc.x+bmd.y, amc.y-bmd.x)
  t3 = __builtin_elementwise_fma(bs, MP, amc);   // (amc.x-bmd.y, amc.y+bmd.x)
}

// Per-stage base twiddles only (6 VGPRs); w2, w3 recomputed inline (R11).
struct TW {
  v2f a1, b1, c1;
};

__device__ __forceinline__ void load_tw(const v2f* __restrict__ W256f, int lane, TW& t) {
  t.a1 = W256f[lane];
  t.b1 = W256f[4 * (lane >> 2)];
  t.c1 = W256f[16 * (lane >> 4)];
}

// 256-pt forward complex FFT. Input regs z0..z3 = z[lane+64m]; output regs
// z0..z3 = Z[lane+64m]. Stages 0 & 3 in registers; 1 & 2 via wave-private LDS.
__device__ __forceinline__ void fft256_reg(v2f& z0, v2f& z1, v2f& z2, v2f& z3,
                                           v2f* __restrict__ buf, int lane, const TW& tw) {
  v2f y0, t1, t2, t3;
  // stage 0 (s=1, p=lane): pure register butterfly, scatter 4l..4l+3
  r4bf(z0, z1, z2, z3, y0, t1, t2, t3);
  {
    v2f w1 = tw.a1, w2 = cmulv(w1, w1), w3 = cmulv(w1, w2);
    int o0 = 4 * lane;
    buf[SWZ(o0)]     = y0;
    buf[SWZ(o0 + 1)] = cmulv(w1, t1);
    buf[SWZ(o0 + 2)] = cmulv(w2, t2);
    buf[SWZ(o0 + 3)] = cmulv(w3, t3);
  }
  wave_sync();
  // stage 1 (s=4)
  {
    v2f a = buf[SWZ(lane)], b = buf[SWZ(lane + 64)],
        c = buf[SWZ(lane + 128)], d = buf[SWZ(lane + 192)];
    wave_sync();
    r4bf(a, b, c, d, y0, t1, t2, t3);
    v2f w1 = tw.b1, w2 = cmulv(w1, w1), w3 = cmulv(w1, w2);
    int o = lane + 12 * (lane >> 2);
    buf[SWZ(o)]      = y0;
    buf[SWZ(o + 4)]  = cmulv(w1, t1);
    buf[SWZ(o + 8)]  = cmulv(w2, t2);
    buf[SWZ(o + 12)] = cmulv(w3, t3);
  }
  wave_sync();
  // stage 2 (s=16)
  {
    v2f a = buf[SWZ(lane)], b = buf[SWZ(lane + 64)],
        c = buf[SWZ(lane + 128)], d = buf[SWZ(lane + 192)];
    wave_sync();
    r4bf(a, b, c, d, y0, t1, t2, t3);
    v2f w1 = tw.c1, w2 = cmulv(w1, w1), w3 = cmulv(w1, w2);
    int o = lane + 48 * (lane >> 4);
    buf[SWZ(o)]      = y0;
    buf[SWZ(o + 16)] = cmulv(w1, t1);
    buf[SWZ(o + 32)] = cmulv(w2, t2);
    buf[SWZ(o + 48)] = cmulv(w3, t3);
  }
  wave_sync();
  // stage 3 (s=64, p=0, twiddle-free): outputs land in register layout
  {
    v2f a = buf[SWZ(lane)], b = buf[SWZ(lane + 64)],
        c = buf[SWZ(lane + 128)], d = buf[SWZ(lane + 192)];
    wave_sync();
    r4bf(a, b, c, d, z0, z1, z2, z3);
  }
}

// W256f[m] = exp(-2pi i m/256), m<256 ; W512s[k] = exp(-2pi i k/512), k<=256
__device__ __forceinline__ void build_tables(v2f* W256f, v2f* W512s) {
  int tid = threadIdx.x;
  float sv, cv;
  __sincosf(-(TWOPI / 256.0f) * (float)tid, &sv, &cv);
  W256f[tid] = (v2f){cv, sv};
  __sincosf(-(TWOPI / 512.0f) * (float)tid, &sv, &cv);
  W512s[tid] = (v2f){cv, sv};
  if (tid == 0) W512s[256] = (v2f){-1.f, 0.f};
}

// ---------------------------------------------------------------------------
// 1) channel mix: y[b,d,t] = sum_c x[b,c,t] * mixer[c,d]   (fp16 output)
//    mixer read directly (wave-uniform -> scalar loads via K$).
// ---------------------------------------------------------------------------
__global__ __launch_bounds__(256) void mix_kernel(const float* __restrict__ x,
                                                  const float* __restrict__ mixer,
                                                  __half2* __restrict__ y) {
  int b = blockIdx.y;
  int t2 = blockIdx.x * 256 + threadIdx.x;     // float2-pair index
  const float2* xv = (const float2*)x;
  float2 xr[NCH];
#pragma unroll
  for (int c = 0; c < NCH; c++)
    xr[c] = xv[(((size_t)(b * NCH + c)) * T_LEN >> 1) + t2];
#pragma unroll 4
  for (int d = 0; d < NCH; d++) {
    float ax = 0.f, ay = 0.f;
#pragma unroll
    for (int c = 0; c < NCH; c++) {
      float m = mixer[c * NCH + d];            // uniform -> s_load
      ax = fmaf(xr[c].x, m, ax);
      ay = fmaf(xr[c].y, m, ay);
    }
    y[(((size_t)(b * NCH + d)) * T_LEN >> 1) + t2] = __float22half2_rn(make_float2(ax, ay));
  }
}

// ---------------------------------------------------------------------------
// 2) forward rfft(512) + register-local scan. Wave = one 4-frame chunk.
//    Chunk burst-loaded as 10 packed half2 segments before the loop
//    (overlapping frame halves share registers; R10-proven correct).
// ---------------------------------------------------------------------------
__global__ __launch_bounds__(256, 3) void fft_fwd_kernel(const __half2* __restrict__ y,
                                                         const float* __restrict__ transfer,
                                                         __half2* __restrict__ spec) {
  __shared__ v2f fbuf[4][NBIN];          // wave-private FFT/mirror buffer
  __shared__ v2f W256f[256];
  __shared__ v2f W512s[NBIN];
  build_tables(W256f, W512s);
  __syncthreads();
  const v2f PM = {1.f, -1.f};
  int wave = threadIdx.x >> 6, lane = threadIdx.x & 63;
  int cid = blockIdx.x * 4 + wave;       // chunk id 0..16383
  int bc = cid >> 7, blk = cid & (NBLK - 1);
  int ch = bc & (NCH - 1);
  v2f* buf = fbuf[wave];
  TW tw; load_tw(W256f, lane, tw);
  v2f Wf[4];
  float trq[4];
#pragma unroll
  for (int q = 0; q < 4; q++) {
    int k = lane + 64 * q;
    Wf[q] = W512s[k];                    // (cw, sw)
    trq[q] = transfer[ch * NBIN + k];
  }
  float tr256 = transfer[ch * NBIN + 256];
  v2f s[4] = {(v2f){0,0}, (v2f){0,0}, (v2f){0,0}, (v2f){0,0}};
  float s256x = 0.f;
  size_t base2 = ((size_t)bc * T_LEN + (size_t)blk * (FPB * HOP)) >> 1;  // half2 idx
  size_t fb = ((size_t)bc * NFR + (size_t)blk * FPB) * NBIN;
  bool lastchunk = (blk == NBLK - 1);
  // burst-load: segment p = samples [128p,128p+128); frame j uses 2j..2j+3
  const __half2* src = y + base2;
  __half2 hz = v2h((v2f){0.f, 0.f});
  __half2 seg[10];
#pragma unroll
  for (int p = 0; p < 10; p++)
    seg[p] = (lastchunk && p >= 8) ? hz : src[(size_t)p * 64 + lane];
#pragma unroll
  for (int j = 0; j < FPB; ++j) {
    v2f z0 = h2v(seg[2 * j]);
    v2f z1 = h2v(seg[2 * j + 1]);
    v2f z2 = h2v(seg[2 * j + 2]);
    v2f z3 = h2v(seg[2 * j + 3]);
    fft256_reg(z0, z1, z2, z3, buf, lane, tw);
    // stage Z (regs) for mirror access
    buf[lane] = z0; buf[lane + 64] = z1; buf[lane + 128] = z2; buf[lane + 192] = z3;
    wave_sync();
    v2f zm0 = buf[(256 - lane) & 255];
    v2f zm1 = buf[192 - lane];
    v2f zm2 = buf[128 - lane];
    v2f zm3 = buf[64 - lane];
    v2f z0b = buf[0];
    wave_sync();
    // untangle + scan + store, k = lane + 64q   (all packed)
#pragma unroll
    for (int q = 0; q < 4; q++) {
      v2f zk  = (q == 0) ? z0 : (q == 1) ? z1 : (q == 2) ? z2 : z3;
      v2f zmk = (q == 0) ? zm0 : (q == 1) ? zm1 : (q == 2) ? zm2 : zm3;
      v2f E = __builtin_elementwise_fma(zmk, PM, zk) * 0.5f;    // (zx+zmx, zy-zmy)/2
      v2f D = __builtin_elementwise_fma(zmk, -PM, zk) * 0.5f;   // (zx-zmx, zy+zmy)/2
      v2f O = D.yx * PM;                                        // (dy, -dx)
      v2f Y = E + cmulv(Wf[q], O);
      s[q] = (Y + s[q]) * trq[q];
      spec[fb + (size_t)j * NBIN + lane + 64 * q] = v2h(s[q]);
    }
    // bin 256: zk = zmk = Z[0], cw=-1, sw=0 -> Y = (Z0.x - Z0.y, 0)
    s256x = tr256 * ((z0b.x - z0b.y) + s256x);
    if (lane == 0) spec[fb + (size_t)j * NBIN + 256] = v2h((v2f){s256x, 0.f});
    wave_sync();
  }
}

// ---------------------------------------------------------------------------
// 3) carry scan across chunks: C[0]=0; C[i] = final[i-1] + tr^FPB * C[i-1]
// ---------------------------------------------------------------------------
__global__ __launch_bounds__(256) void carry_kernel(const __half2* __restrict__ spec,
                                                    const float* __restrict__ transfer,
                                                    __half2* __restrict__ carries) {
  int tid = blockIdx.x * 256 + threadIdx.x;
  if (tid >= NBC * NBIN) return;
  int bc = tid / NBIN, k = tid - bc * NBIN;
  int ch = bc & (NCH - 1);
  float tr = transfer[ch * NBIN + k];
  float tr2 = tr * tr;
  float tr4 = tr2 * tr2;          // tr^FPB
  const __half2* fin = spec + (size_t)bc * NFR * NBIN + (size_t)(FPB - 1) * NBIN + k;
  __half2* cp = carries + (size_t)bc * NBLK * NBIN + k;
  v2f c = {0.f, 0.f};
  for (int i = 0; i < NBLK; i += 16) {
    v2f v[16];
#pragma unroll
    for (int u = 0; u < 16; u++) v[u] = h2v(fin[(size_t)(i + u) * FPB * NBIN]);
#pragma unroll
    for (int u = 0; u < 16; u++) {
      cp[(size_t)(i + u) * NBIN] = v2h(c);
      c = __builtin_elementwise_fma((v2f){tr4, tr4}, c, v[u]);
    }
  }
}

// ---------------------------------------------------------------------------
// 4) inverse rfft + hann + register OLA. Wave = one 4-frame chunk.
//    Chunk's spectra burst-loaded before the loop (20 packed half2 regs,
//    statically indexed). Mirror via ds_bpermute (R15-proven).
// ---------------------------------------------------------------------------
__global__ __launch_bounds__(256, 3) void fft_inv_kernel(const __half2* __restrict__ spec,
                                                         const __half2* __restrict__ carries,
                                                         const float* __restrict__ transfer,
                                                         const float* __restrict__ gain,
                                                         float* __restrict__ out,
                                                         __half2* __restrict__ bnd) {
  __shared__ v2f fbuf[4][NBIN];
  __shared__ v2f W256f[256];
  __shared__ v2f W512s[NBIN];
  build_tables(W256f, W512s);
  __syncthreads();
  const v2f PM = {1.f, -1.f};
  int wave = threadIdx.x >> 6, lane = threadIdx.x & 63;
  int cid = blockIdx.x * 4 + wave;
  int bc = cid >> 7, blk = cid & (NBLK - 1);
  int ch = bc & (NCH - 1);
  v2f* buf = fbuf[wave];
  TW tw; load_tw(W256f, lane, tw);
  const __half2* crp = carries + ((size_t)bc * NBLK + blk) * NBIN;
  const __half2* sp0 = spec + ((size_t)bc * NFR + (size_t)blk * FPB) * NBIN;
  // burst-load the whole chunk's spectra (fully unrolled -> registers)
  __half2 S0[FPB], S1[FPB], S2[FPB], S3[FPB], S256[FPB];
#pragma unroll
  for (int j = 0; j < FPB; j++) {
    const __half2* sp = sp0 + (size_t)j * NBIN;
    S0[j] = sp[lane];
    S1[j] = sp[lane + 64];
    S2[j] = sp[lane + 128];
    S3[j] = sp[lane + 192];
    S256[j] = sp[256];
  }
  v2f Wi[4], cv[4], hv[4];
  float trq[4], trp[4];
#pragma unroll
  for (int q = 0; q < 4; q++) {
    int k = lane + 64 * q;
    Wi[q] = W512s[k] * PM;               // (cw, -sw) = exp(+2pi i k/512)
    trq[q] = transfer[ch * NBIN + k];
    trp[q] = trq[q];
    cv[q] = h2v(crp[k]);
    int t0 = 2 * k, t1 = 2 * k + 1;
    int i0 = (t0 <= 256) ? t0 : 512 - t0;
    int i1 = (t1 <= 256) ? t1 : 512 - t1;
    float h0 = (0.5f - 0.5f * W512s[i0].x) * (1.0f / 256.0f);
    float h1 = (0.5f - 0.5f * W512s[i1].x) * (1.0f / 256.0f);
    hv[q] = (v2f){h0, -h1};              // window + conj fold: w = z * (h0, -h1)
  }
  float tr256 = transfer[ch * NBIN + 256], trp256 = tr256;
  v2f cv256 = h2v(crp[256]);
  float g = gain[ch];
  float2* outv = (float2*)out;
  size_t obase2 = ((size_t)bc * T_LEN + (size_t)blk * (FPB * HOP)) >> 1;
  __half2* bp = bnd + (((size_t)bc * NBLK + blk) * 2) * (HOP / 2);
  int maddr = ((64 - lane) & 63) << 2;   // bpermute byte addr: src lane 64-l
  v2f pt0, pt1;                          // previous frame's windowed tail
#pragma unroll
  for (int j = 0; j < FPB; ++j) {
    // carry fix-up: O = local + tr^(j+1) * carry   (packed fma)
    v2f Y0 = __builtin_elementwise_fma((v2f){trp[0], trp[0]}, cv[0], h2v(S0[j]));
    v2f Y1 = __builtin_elementwise_fma((v2f){trp[1], trp[1]}, cv[1], h2v(S1[j]));
    v2f Y2 = __builtin_elementwise_fma((v2f){trp[2], trp[2]}, cv[2], h2v(S2[j]));
    v2f Y3 = __builtin_elementwise_fma((v2f){trp[3], trp[3]}, cv[3], h2v(S3[j]));
    v2f y256 = __builtin_elementwise_fma((v2f){trp256, trp256}, cv256, h2v(S256[j]));
#pragma unroll
    for (int q = 0; q < 4; q++) trp[q] *= trq[q];
    trp256 *= tr256;
    // mirror via crossbar: ym[q] = Y[256-k], k = lane+64q
    //   lane>=1: reg (3-q) @ src lane 64-lane ; lane==0: own-reg fixups
    v2f ym0 = bperm2(maddr, Y3);
    v2f ym1 = bperm2(maddr, Y2);
    v2f ym2 = bperm2(maddr, Y1);
    v2f ym3 = bperm2(maddr, Y0);
    if (lane == 0) { ym0 = y256; ym1 = Y3; ym2 = Y2; ym3 = Y1; }
    // inverse untangle -> conj'd FFT input:  z = E*PM - O.yx   (packed)
    v2f z0, z1, z2, z3;
#pragma unroll
    for (int q = 0; q < 4; q++) {
      v2f yk  = (q == 0) ? Y0 : (q == 1) ? Y1 : (q == 2) ? Y2 : Y3;
      v2f ymk = (q == 0) ? ym0 : (q == 1) ? ym1 : (q == 2) ? ym2 : ym3;
      v2f E = __builtin_elementwise_fma(ymk, PM, yk) * 0.5f;
      v2f D = __builtin_elementwise_fma(ymk, -PM, yk) * 0.5f;
      v2f O = cmulv(Wi[q], D);           // (dx cw - dy sw, dx sw + dy cw)
      v2f zq = E * PM - O.yx;            // (Ex - Oy, -(Ey + Ox))
      if (q == 0) z0 = zq; else if (q == 1) z1 = zq; else if (q == 2) z2 = zq; else z3 = zq;
    }
    fft256_reg(z0, z1, z2, z3, buf, lane, tw);
    // windowed time samples: w = z * (h0, -h1)   (conj + /256 folded in)
    v2f w0 = z0 * hv[0];
    v2f w1 = z1 * hv[1];
    v2f w2 = z2 * hv[2];
    v2f w3 = z3 * hv[3];
    if (j == 0) {
      bp[lane]      = v2h(w0);           // chunk-leading head -> bnd
      bp[lane + 64] = v2h(w1);
    } else {
      v2f v0 = pt0 + w0;
      v2f v1 = pt1 + w1;
      outv[obase2 + (size_t)j * 128 + lane] =
          make_float2(fast_tanh(g * v0.x), fast_tanh(g * v0.y));
      outv[obase2 + (size_t)j * 128 + lane + 64] =
          make_float2(fast_tanh(g * v1.x), fast_tanh(g * v1.y));
    }
    pt0 = w2; pt1 = w3;
    wave_sync();                         // next frame's stage-0 writes wait
  }
  bp[128 + lane] = v2h(pt0);             // chunk-trailing tail -> bnd
  bp[192 + lane] = v2h(pt1);
}

// ---------------------------------------------------------------------------
// 5) combine boundary chunks: chunk FPB*b <- bnd[b-1].tail + bnd[b].head
// ---------------------------------------------------------------------------
__global__ __launch_bounds__(256) void final_kernel(const __half* __restrict__ bnd,
                                                    const float* __restrict__ gain,
                                                    float* __restrict__ out) {
  int bc = blockIdx.y, b = blockIdx.x;
  int s = threadIdx.x;
  const __half* base = bnd + ((size_t)bc * NBLK) * 2 * HOP;
  float v = __half2float(base[((size_t)b * 2) * HOP + s]);
  if (b > 0) v += __half2float(base[((size_t)(b - 1) * 2 + 1) * HOP + s]);
  float g = gain[bc & (NCH - 1)];
  out[(size_t)bc * T_LEN + (size_t)b * (FPB * HOP) + s] = fast_tanh(g * v);
}

// ---------------------------------------------------------------------------
extern "C" void kernel_launch(void* const* d_in, const int* in_sizes, int n_in,
                              void* d_out, int out_size, void* d_ws, size_t ws_size,
                              hipStream_t stream) {
  (void)in_sizes; (void)n_in; (void)out_size; (void)ws_size;
  const float* x        = (const float*)d_in[0];
  const float* transfer = (const float*)d_in[1];
  const float* mixer    = (const float*)d_in[2];
  const float* gain     = (const float*)d_in[3];
  float* out = (float*)d_out;

  // ws layout (all fp16):
  //  [spec 67,371,008 B][bnd 16,777,216 B][carries 16,842,752 B][y 33,554,432 B]
  char* p = (char*)d_ws;
  __half2* spec    = (__half2*)p;                       p += (size_t)NBC * NFR * NBIN * 4;
  __half2* bnd     = (__half2*)p;                       p += (size_t)NBC * NBLK * 2 * HOP * 2;
  __half2* carries = (__half2*)p;                       p += (size_t)NBC * NBLK * NBIN * 4;
  __half2* y       = (__half2*)p;

  mix_kernel<<<dim3(T_LEN / 512, NBAT), 256, 0, stream>>>(x, mixer, y);
  fft_fwd_kernel<<<dim3(NBC * NBLK / 4), 256, 0, stream>>>(y, transfer, spec);
  carry_kernel<<<dim3((NBC * NBIN + 255) / 256), 256, 0, stream>>>(spec, transfer, carries);
  fft_inv_kernel<<<dim3(NBC * NBLK / 4), 256, 0, stream>>>(spec, carries, transfer, gain, out, (__half2*)bnd);
  final_kernel<<<dim3(NBLK, NBC), 256, 0, stream>>>((const __half*)bnd, gain, out);
}

// Round 18
// 102.944 us; speedup vs baseline: 1.1080x; 1.0609x over previous
//
#include <hip/hip_runtime.h>
#include <hip/hip_fp16.h>
#include <math.h>

// Problem constants
#define T_LEN 131072
#define NCH   32
#define NBAT  4
#define WIN   512
#define HOP   256
#define NFR   512            // frames per (b,c) = T/HOP
#define NBIN  257            // rfft bins
#define NBC   (NBAT*NCH)     // 128
#define FPB   8              // frames per chunk (one wave per chunk)
#define NBLK  (NFR/FPB)      // 64 chunks per bc
#define NSEG  (FPB*2 + 2)    // 18 128-sample segments cover a chunk+overlap
#define TWOPI 6.28318530717958647692f

// XOR swizzle for FFT LDS complex arrays (hits the b64 4-lane/bank floor)
#define SWZ(m) ((m) ^ ((((m) >> 4) & 15)))

// Packed complex type: clang emits v_pk_{add,mul,fma}_f32 for ext_vector
// float2 arithmetic on CDNA — halves VALU instruction count vs scalar pairs.
typedef float v2f __attribute__((ext_vector_type(2)));

__device__ __forceinline__ v2f cmulv(v2f u, v2f v) {
  // (ux vx - uy vy, ux vy + uy vx) = u.xx*v + (-uy, uy)*v.yx  -> 2 pk_fma
  v2f r = u.xx * v;
  return __builtin_elementwise_fma((v2f){-u.y, u.y}, v.yx, r);
}

__device__ __forceinline__ float fast_tanh(float x) {
  float e = __expf(2.0f * x);                    // inf-safe
  return 1.0f - 2.0f * __builtin_amdgcn_rcpf(e + 1.0f);
}

__device__ __forceinline__ v2f h2v(__half2 h) {
  float2 f = __half22float2(h);
  return (v2f){f.x, f.y};
}
__device__ __forceinline__ __half2 v2h(v2f v) {
  return __float22half2_rn(make_float2(v.x, v.y));
}

// Cross-lane pull via the LDS crossbar (no LDS storage, no fences, no
// bank conflicts). R10/R15-proven form: extract scalars, __float_as_int.
__device__ __forceinline__ v2f bperm2(int addr, v2f v) {
  float fx = v.x, fy = v.y;
  int vx = __builtin_amdgcn_ds_bpermute(addr, __float_as_int(fx));
  int vy = __builtin_amdgcn_ds_bpermute(addr, __float_as_int(fy));
  return (v2f){__int_as_float(vx), __int_as_float(vy)};
}

// Wave-level ordering fence: LDS ops of a wave execute in order on the DS
// pipe; this only stops compiler reordering (no s_barrier, no cnt drain).
// Burst global loads are issued BEFORE the loop so they stay in flight.
__device__ __forceinline__ void wave_sync() {
  asm volatile("" ::: "memory");
  __builtin_amdgcn_wave_barrier();
  asm volatile("" ::: "memory");
}

// radix-4 DIF butterfly (packed): t1 = amc - i*bmd, t3 = amc + i*bmd
__device__ __forceinline__ void r4bf(v2f a, v2f b, v2f c, v2f d,
                                     v2f& y0, v2f& t1, v2f& t2, v2f& t3) {
  const v2f PM = {1.f, -1.f};
  const v2f MP = {-1.f, 1.f};
  v2f apc = a + c, amc = a - c;
  v2f bpd = b + d, bmd = b - d;
  y0 = apc + bpd;
  t2 = apc - bpd;
  v2f bs = bmd.yx;
  t1 = __builtin_elementwise_fma(bs, PM, amc);   // (amc.x+bmd.y, amc.y-bmd.x)
  t3 = __builtin_elementwise_fma(bs, MP, amc);   // (amc.x-bmd.y, amc.y+bmd.x)
}

// Per-stage base twiddles only (6 VGPRs); w2, w3 recomputed inline (R11).
struct TW {
  v2f a1, b1, c1;
};

__device__ __forceinline__ void load_tw(const v2f* __restrict__ W256f, int lane, TW& t) {
  t.a1 = W256f[lane];
  t.b1 = W256f[4 * (lane >> 2)];
  t.c1 = W256f[16 * (lane >> 4)];
}

// 256-pt forward complex FFT. Input regs z0..z3 = z[lane+64m]; output regs
// z0..z3 = Z[lane+64m]. Stages 0 & 3 in registers; 1 & 2 via wave-private LDS.
__device__ __forceinline__ void fft256_reg(v2f& z0, v2f& z1, v2f& z2, v2f& z3,
                                           v2f* __restrict__ buf, int lane, const TW& tw) {
  v2f y0, t1, t2, t3;
  // stage 0 (s=1, p=lane): pure register butterfly, scatter 4l..4l+3
  r4bf(z0, z1, z2, z3, y0, t1, t2, t3);
  {
    v2f w1 = tw.a1, w2 = cmulv(w1, w1), w3 = cmulv(w1, w2);
    int o0 = 4 * lane;
    buf[SWZ(o0)]     = y0;
    buf[SWZ(o0 + 1)] = cmulv(w1, t1);
    buf[SWZ(o0 + 2)] = cmulv(w2, t2);
    buf[SWZ(o0 + 3)] = cmulv(w3, t3);
  }
  wave_sync();
  // stage 1 (s=4)
  {
    v2f a = buf[SWZ(lane)], b = buf[SWZ(lane + 64)],
        c = buf[SWZ(lane + 128)], d = buf[SWZ(lane + 192)];
    wave_sync();
    r4bf(a, b, c, d, y0, t1, t2, t3);
    v2f w1 = tw.b1, w2 = cmulv(w1, w1), w3 = cmulv(w1, w2);
    int o = lane + 12 * (lane >> 2);
    buf[SWZ(o)]      = y0;
    buf[SWZ(o + 4)]  = cmulv(w1, t1);
    buf[SWZ(o + 8)]  = cmulv(w2, t2);
    buf[SWZ(o + 12)] = cmulv(w3, t3);
  }
  wave_sync();
  // stage 2 (s=16)
  {
    v2f a = buf[SWZ(lane)], b = buf[SWZ(lane + 64)],
        c = buf[SWZ(lane + 128)], d = buf[SWZ(lane + 192)];
    wave_sync();
    r4bf(a, b, c, d, y0, t1, t2, t3);
    v2f w1 = tw.c1, w2 = cmulv(w1, w1), w3 = cmulv(w1, w2);
    int o = lane + 48 * (lane >> 4);
    buf[SWZ(o)]      = y0;
    buf[SWZ(o + 16)] = cmulv(w1, t1);
    buf[SWZ(o + 32)] = cmulv(w2, t2);
    buf[SWZ(o + 48)] = cmulv(w3, t3);
  }
  wave_sync();
  // stage 3 (s=64, p=0, twiddle-free): outputs land in register layout
  {
    v2f a = buf[SWZ(lane)], b = buf[SWZ(lane + 64)],
        c = buf[SWZ(lane + 128)], d = buf[SWZ(lane + 192)];
    wave_sync();
    r4bf(a, b, c, d, z0, z1, z2, z3);
  }
}

// W256f[m] = exp(-2pi i m/256), m<256 ; W512s[k] = exp(-2pi i k/512), k<=256
__device__ __forceinline__ void build_tables(v2f* W256f, v2f* W512s) {
  int tid = threadIdx.x;
  float sv, cv;
  __sincosf(-(TWOPI / 256.0f) * (float)tid, &sv, &cv);
  W256f[tid] = (v2f){cv, sv};
  __sincosf(-(TWOPI / 512.0f) * (float)tid, &sv, &cv);
  W512s[tid] = (v2f){cv, sv};
  if (tid == 0) W512s[256] = (v2f){-1.f, 0.f};
}

// ---------------------------------------------------------------------------
// 1) channel mix: y[b,d,t] = sum_c x[b,c,t] * mixer[c,d]   (fp16 output)
//    mixer read directly (wave-uniform -> scalar loads via K$).
// ---------------------------------------------------------------------------
__global__ __launch_bounds__(256) void mix_kernel(const float* __restrict__ x,
                                                  const float* __restrict__ mixer,
                                                  __half2* __restrict__ y) {
  int b = blockIdx.y;
  int t2 = blockIdx.x * 256 + threadIdx.x;     // float2-pair index
  const float2* xv = (const float2*)x;
  float2 xr[NCH];
#pragma unroll
  for (int c = 0; c < NCH; c++)
    xr[c] = xv[(((size_t)(b * NCH + c)) * T_LEN >> 1) + t2];
#pragma unroll 4
  for (int d = 0; d < NCH; d++) {
    float ax = 0.f, ay = 0.f;
#pragma unroll
    for (int c = 0; c < NCH; c++) {
      float m = mixer[c * NCH + d];            // uniform -> s_load
      ax = fmaf(xr[c].x, m, ax);
      ay = fmaf(xr[c].y, m, ay);
    }
    y[(((size_t)(b * NCH + d)) * T_LEN >> 1) + t2] = __float22half2_rn(make_float2(ax, ay));
  }
}

// ---------------------------------------------------------------------------
// 2) forward rfft(512) + register-local scan. Wave = one 8-frame chunk.
//    Chunk burst-loaded as 18 packed half2 segments before the loop
//    (overlapping frame halves share registers).
// ---------------------------------------------------------------------------
__global__ __launch_bounds__(256, 3) void fft_fwd_kernel(const __half2* __restrict__ y,
                                                         const float* __restrict__ transfer,
                                                         __half2* __restrict__ spec) {
  __shared__ v2f fbuf[4][NBIN];          // wave-private FFT/mirror buffer
  __shared__ v2f W256f[256];
  __shared__ v2f W512s[NBIN];
  build_tables(W256f, W512s);
  __syncthreads();
  const v2f PM = {1.f, -1.f};
  int wave = threadIdx.x >> 6, lane = threadIdx.x & 63;
  int cid = blockIdx.x * 4 + wave;       // chunk id 0..8191
  int bc = cid >> 6, blk = cid & (NBLK - 1);
  int ch = bc & (NCH - 1);
  v2f* buf = fbuf[wave];
  TW tw; load_tw(W256f, lane, tw);
  v2f Wf[4];
  float trq[4];
#pragma unroll
  for (int q = 0; q < 4; q++) {
    int k = lane + 64 * q;
    Wf[q] = W512s[k];                    // (cw, sw)
    trq[q] = transfer[ch * NBIN + k];
  }
  float tr256 = transfer[ch * NBIN + 256];
  v2f s[4] = {(v2f){0,0}, (v2f){0,0}, (v2f){0,0}, (v2f){0,0}};
  float s256x = 0.f;
  size_t base2 = ((size_t)bc * T_LEN + (size_t)blk * (FPB * HOP)) >> 1;  // half2 idx
  size_t fb = ((size_t)bc * NFR + (size_t)blk * FPB) * NBIN;
  bool lastchunk = (blk == NBLK - 1);
  // burst-load: segment p = samples [128p,128p+128); frame j uses 2j..2j+3
  const __half2* src = y + base2;
  __half2 hz = v2h((v2f){0.f, 0.f});
  __half2 seg[NSEG];
#pragma unroll
  for (int p = 0; p < NSEG; p++)
    seg[p] = (lastchunk && p >= NSEG - 2) ? hz : src[(size_t)p * 64 + lane];
#pragma unroll
  for (int j = 0; j < FPB; ++j) {
    v2f z0 = h2v(seg[2 * j]);
    v2f z1 = h2v(seg[2 * j + 1]);
    v2f z2 = h2v(seg[2 * j + 2]);
    v2f z3 = h2v(seg[2 * j + 3]);
    fft256_reg(z0, z1, z2, z3, buf, lane, tw);
    // stage Z (regs) for mirror access
    buf[lane] = z0; buf[lane + 64] = z1; buf[lane + 128] = z2; buf[lane + 192] = z3;
    wave_sync();
    v2f zm0 = buf[(256 - lane) & 255];
    v2f zm1 = buf[192 - lane];
    v2f zm2 = buf[128 - lane];
    v2f zm3 = buf[64 - lane];
    v2f z0b = buf[0];
    wave_sync();
    // untangle + scan + store, k = lane + 64q   (all packed)
#pragma unroll
    for (int q = 0; q < 4; q++) {
      v2f zk  = (q == 0) ? z0 : (q == 1) ? z1 : (q == 2) ? z2 : z3;
      v2f zmk = (q == 0) ? zm0 : (q == 1) ? zm1 : (q == 2) ? zm2 : zm3;
      v2f E = __builtin_elementwise_fma(zmk, PM, zk) * 0.5f;    // (zx+zmx, zy-zmy)/2
      v2f D = __builtin_elementwise_fma(zmk, -PM, zk) * 0.5f;   // (zx-zmx, zy+zmy)/2
      v2f O = D.yx * PM;                                        // (dy, -dx)
      v2f Y = E + cmulv(Wf[q], O);
      s[q] = (Y + s[q]) * trq[q];
      spec[fb + (size_t)j * NBIN + lane + 64 * q] = v2h(s[q]);
    }
    // bin 256: zk = zmk = Z[0], cw=-1, sw=0 -> Y = (Z0.x - Z0.y, 0)
    s256x = tr256 * ((z0b.x - z0b.y) + s256x);
    if (lane == 0) spec[fb + (size_t)j * NBIN + 256] = v2h((v2f){s256x, 0.f});
    wave_sync();
  }
}

// ---------------------------------------------------------------------------
// 3) carry scan across chunks: C[0]=0; C[i] = final[i-1] + tr^FPB * C[i-1]
// ---------------------------------------------------------------------------
__global__ __launch_bounds__(256) void carry_kernel(const __half2* __restrict__ spec,
                                                    const float* __restrict__ transfer,
                                                    __half2* __restrict__ carries) {
  int tid = blockIdx.x * 256 + threadIdx.x;
  if (tid >= NBC * NBIN) return;
  int bc = tid / NBIN, k = tid - bc * NBIN;
  int ch = bc & (NCH - 1);
  float tr = transfer[ch * NBIN + k];
  float tr2 = tr * tr;
  float tr4 = tr2 * tr2;
  float tr8 = tr4 * tr4;          // tr^FPB
  const __half2* fin = spec + (size_t)bc * NFR * NBIN + (size_t)(FPB - 1) * NBIN + k;
  __half2* cp = carries + (size_t)bc * NBLK * NBIN + k;
  v2f c = {0.f, 0.f};
  for (int i = 0; i < NBLK; i += 16) {
    v2f v[16];
#pragma unroll
    for (int u = 0; u < 16; u++) v[u] = h2v(fin[(size_t)(i + u) * FPB * NBIN]);
#pragma unroll
    for (int u = 0; u < 16; u++) {
      cp[(size_t)(i + u) * NBIN] = v2h(c);
      c = __builtin_elementwise_fma((v2f){tr8, tr8}, c, v[u]);
    }
  }
}

// ---------------------------------------------------------------------------
// 4) inverse rfft + hann + register OLA. Wave = one 8-frame chunk.
//    Chunk's spectra burst-loaded before the loop (40 packed half2 regs,
//    statically indexed). Mirror via ds_bpermute.
// ---------------------------------------------------------------------------
__global__ __launch_bounds__(256, 3) void fft_inv_kernel(const __half2* __restrict__ spec,
                                                         const __half2* __restrict__ carries,
                                                         const float* __restrict__ transfer,
                                                         const float* __restrict__ gain,
                                                         float* __restrict__ out,
                                                         __half2* __restrict__ bnd) {
  __shared__ v2f fbuf[4][NBIN];
  __shared__ v2f W256f[256];
  __shared__ v2f W512s[NBIN];
  build_tables(W256f, W512s);
  __syncthreads();
  const v2f PM = {1.f, -1.f};
  int wave = threadIdx.x >> 6, lane = threadIdx.x & 63;
  int cid = blockIdx.x * 4 + wave;
  int bc = cid >> 6, blk = cid & (NBLK - 1);
  int ch = bc & (NCH - 1);
  v2f* buf = fbuf[wave];
  TW tw; load_tw(W256f, lane, tw);
  const __half2* crp = carries + ((size_t)bc * NBLK + blk) * NBIN;
  const __half2* sp0 = spec + ((size_t)bc * NFR + (size_t)blk * FPB) * NBIN;
  // burst-load the whole chunk's spectra (fully unrolled -> registers)
  __half2 S0[FPB], S1[FPB], S2[FPB], S3[FPB], S256[FPB];
#pragma unroll
  for (int j = 0; j < FPB; j++) {
    const __half2* sp = sp0 + (size_t)j * NBIN;
    S0[j] = sp[lane];
    S1[j] = sp[lane + 64];
    S2[j] = sp[lane + 128];
    S3[j] = sp[lane + 192];
    S256[j] = sp[256];
  }
  v2f Wi[4], cv[4], hv[4];
  float trq[4], trp[4];
#pragma unroll
  for (int q = 0; q < 4; q++) {
    int k = lane + 64 * q;
    Wi[q] = W512s[k] * PM;               // (cw, -sw) = exp(+2pi i k/512)
    trq[q] = transfer[ch * NBIN + k];
    trp[q] = trq[q];
    cv[q] = h2v(crp[k]);
    int t0 = 2 * k, t1 = 2 * k + 1;
    int i0 = (t0 <= 256) ? t0 : 512 - t0;
    int i1 = (t1 <= 256) ? t1 : 512 - t1;
    float h0 = (0.5f - 0.5f * W512s[i0].x) * (1.0f / 256.0f);
    float h1 = (0.5f - 0.5f * W512s[i1].x) * (1.0f / 256.0f);
    hv[q] = (v2f){h0, -h1};              // window + conj fold: w = z * (h0, -h1)
  }
  float tr256 = transfer[ch * NBIN + 256], trp256 = tr256;
  v2f cv256 = h2v(crp[256]);
  float g = gain[ch];
  float2* outv = (float2*)out;
  size_t obase2 = ((size_t)bc * T_LEN + (size_t)blk * (FPB * HOP)) >> 1;
  __half2* bp = bnd + (((size_t)bc * NBLK + blk) * 2) * (HOP / 2);
  int maddr = ((64 - lane) & 63) << 2;   // bpermute byte addr: src lane 64-l
  v2f pt0, pt1;                          // previous frame's windowed tail
#pragma unroll
  for (int j = 0; j < FPB; ++j) {
    // carry fix-up: O = local + tr^(j+1) * carry   (packed fma)
    v2f Y0 = __builtin_elementwise_fma((v2f){trp[0], trp[0]}, cv[0], h2v(S0[j]));
    v2f Y1 = __builtin_elementwise_fma((v2f){trp[1], trp[1]}, cv[1], h2v(S1[j]));
    v2f Y2 = __builtin_elementwise_fma((v2f){trp[2], trp[2]}, cv[2], h2v(S2[j]));
    v2f Y3 = __builtin_elementwise_fma((v2f){trp[3], trp[3]}, cv[3], h2v(S3[j]));
    v2f y256 = __builtin_elementwise_fma((v2f){trp256, trp256}, cv256, h2v(S256[j]));
#pragma unroll
    for (int q = 0; q < 4; q++) trp[q] *= trq[q];
    trp256 *= tr256;
    // mirror via crossbar: ym[q] = Y[256-k], k = lane+64q
    //   lane>=1: reg (3-q) @ src lane 64-lane ; lane==0: own-reg fixups
    v2f ym0 = bperm2(maddr, Y3);
    v2f ym1 = bperm2(maddr, Y2);
    v2f ym2 = bperm2(maddr, Y1);
    v2f ym3 = bperm2(maddr, Y0);
    if (lane == 0) { ym0 = y256; ym1 = Y3; ym2 = Y2; ym3 = Y1; }
    // inverse untangle -> conj'd FFT input:  z = E*PM - O.yx   (packed)
    v2f z0, z1, z2, z3;
#pragma unroll
    for (int q = 0; q < 4; q++) {
      v2f yk  = (q == 0) ? Y0 : (q == 1) ? Y1 : (q == 2) ? Y2 : Y3;
      v2f ymk = (q == 0) ? ym0 : (q == 1) ? ym1 : (q == 2) ? ym2 : ym3;
      v2f E = __builtin_elementwise_fma(ymk, PM, yk) * 0.5f;
      v2f D = __builtin_elementwise_fma(ymk, -PM, yk) * 0.5f;
      v2f O = cmulv(Wi[q], D);           // (dx cw - dy sw, dx sw + dy cw)
      v2f zq = E * PM - O.yx;            // (Ex - Oy, -(Ey + Ox))
      if (q == 0) z0 = zq; else if (q == 1) z1 = zq; else if (q == 2) z2 = zq; else z3 = zq;
    }
    fft256_reg(z0, z1, z2, z3, buf, lane, tw);
    // windowed time samples: w = z * (h0, -h1)   (conj + /256 folded in)
    v2f w0 = z0 * hv[0];
    v2f w1 = z1 * hv[1];
    v2f w2 = z2 * hv[2];
    v2f w3 = z3 * hv[3];
    if (j == 0) {
      bp[lane]      = v2h(w0);           // chunk-leading head -> bnd
      bp[lane + 64] = v2h(w1);
    } else {
      v2f v0 = pt0 + w0;
      v2f v1 = pt1 + w1;
      outv[obase2 + (size_t)j * 128 + lane] =
          make_float2(fast_tanh(g * v0.x), fast_tanh(g * v0.y));
      outv[obase2 + (size_t)j * 128 + lane + 64] =
          make_float2(fast_tanh(g * v1.x), fast_tanh(g * v1.y));
    }
    pt0 = w2; pt1 = w3;
    wave_sync();                         // next frame's stage-0 writes wait
  }
  bp[128 + lane] = v2h(pt0);             // chunk-trailing tail -> bnd
  bp[192 + lane] = v2h(pt1);
}

// ---------------------------------------------------------------------------
// 5) combine boundary chunks: chunk FPB*b <- bnd[b-1].tail + bnd[b].head
// ---------------------------------------------------------------------------
__global__ __launch_bounds__(256) void final_kernel(const __half* __restrict__ bnd,
                                                    const float* __restrict__ gain,
                                                    float* __restrict__ out) {
  int bc = blockIdx.y, b = blockIdx.x;
  int s = threadIdx.x;
  const __half* base = bnd + ((size_t)bc * NBLK) * 2 * HOP;
  float v = __half2float(base[((size_t)b * 2) * HOP + s]);
  if (b > 0) v += __half2float(base[((size_t)(b - 1) * 2 + 1) * HOP + s]);
  float g = gain[bc & (NCH - 1)];
  out[(size_t)bc * T_LEN + (size_t)b * (FPB * HOP) + s] = fast_tanh(g * v);
}

// ---------------------------------------------------------------------------
extern "C" void kernel_launch(void* const* d_in, const int* in_sizes, int n_in,
                              void* d_out, int out_size, void* d_ws, size_t ws_size,
                              hipStream_t stream) {
  (void)in_sizes; (void)n_in; (void)out_size; (void)ws_size;
  const float* x        = (const float*)d_in[0];
  const float* transfer = (const float*)d_in[1];
  const float* mixer    = (const float*)d_in[2];
  const float* gain     = (const float*)d_in[3];
  float* out = (float*)d_out;

  // ws layout (all fp16):
  //  [spec 67,371,008 B][bnd 8,388,608 B][carries 8,421,376 B][y 33,554,432 B]
  char* p = (char*)d_ws;
  __half2* spec    = (__half2*)p;                       p += (size_t)NBC * NFR * NBIN * 4;
  __half2* bnd     = (__half2*)p;                       p += (size_t)NBC * NBLK * 2 * HOP * 2;
  __half2* carries = (__half2*)p;                       p += (size_t)NBC * NBLK * NBIN * 4;
  __half2* y       = (__half2*)p;

  mix_kernel<<<dim3(T_LEN / 512, NBAT), 256, 0, stream>>>(x, mixer, y);
  fft_fwd_kernel<<<dim3(NBC * NBLK / 4), 256, 0, stream>>>(y, transfer, spec);
  carry_kernel<<<dim3((NBC * NBIN + 255) / 256), 256, 0, stream>>>(spec, transfer, carries);
  fft_inv_kernel<<<dim3(NBC * NBLK / 4), 256, 0, stream>>>(spec, carries, transfer, gain, out, (__half2*)bnd);
  final_kernel<<<dim3(NBLK, NBC), 256, 0, stream>>>((const __half*)bnd, gain, out);
}